// Round 8
// baseline (109.688 us; speedup 1.0000x reference)
//
#include <hip/hip_runtime.h>
#include <math.h>

// Problem sizes (fixed by reference setup_inputs)
#define BATCH 8
#define NPTS  8192   // pred/full points per batch
#define PPTS  2048   // partial points per batch
#define DLAT  512    // latent dim

typedef __attribute__((ext_vector_type(8)))  short short8;    // 8 bf16 (4 VGPR)
typedef __attribute__((ext_vector_type(16))) float floatx16;  // MFMA 32x32 C/D

// Workspace (float elements):
//   [0..4)    acc: sum_pf, sum_fp, sum_fid, sum_kl   (zeroed by minpass blk 0)
//   [4]       uint completion counter                 (zeroed by minpass blk 0)
//   [8..)     ysplit segments of partial min-d^2, each SEG floats
//             (pf | fp | fid regions). Block-owned plain stores, no init.
#define SEG      (2 * BATCH * NPTS + BATCH * PPTS)   // 147456
#define DIR_PF   0
#define DIR_FP   (BATCH * NPTS)
#define DIR_FID  (2 * BATCH * NPTS)
#define OFF_SEG  8

#define CHUNK  1024  // y per block = one LDS stage (ysplit=8)
#define XBLK   512   // x points per block (4 waves x 4 col-groups of 32)

__device__ __forceinline__ unsigned short f2bf(float f) {  // RNE float->bf16
    unsigned int u = __float_as_uint(f);
    return (unsigned short)((u + 0x7FFFu + ((u >> 16) & 1u)) >> 16);
}
__device__ __forceinline__ float bf2f(unsigned short s) {
    return __uint_as_float(((unsigned int)s) << 16);
}

// min over 16 accumulator regs (16 rows of this lane's column) + carry-in.
// 8 v_min3_f32 + 1 v_min = optimal ternary tree.
__device__ __forceinline__ float min16(floatx16 d, float prev) {
    float a0 = fminf(fminf(d[0],  d[1]),  d[2]);
    float a1 = fminf(fminf(d[3],  d[4]),  d[5]);
    float a2 = fminf(fminf(d[6],  d[7]),  d[8]);
    float a3 = fminf(fminf(d[9],  d[10]), d[11]);
    float a4 = fminf(fminf(d[12], d[13]), d[14]);
    float b0 = fminf(fminf(a0, a1), a2);
    float b1 = fminf(fminf(a3, a4), d[15]);
    return fminf(fminf(b0, b1), prev);
}

// Encode one y point + its norm into two uint4 k-half records.
__device__ __forceinline__ void encodeY(float y0, float y1, float y2,
                                        uint4* r0, uint4* r1) {
    const unsigned short h0 = f2bf(y0), h1 = f2bf(y1), h2 = f2bf(y2);
    const unsigned short l0 = f2bf(y0 - bf2f(h0));
    const unsigned short l1 = f2bf(y1 - bf2f(h1));
    const unsigned short l2 = f2bf(y2 - bf2f(h2));
    const float yn = fmaf(y0, y0, fmaf(y1, y1, y2 * y2));
    const unsigned short nh = f2bf(yn);
    const unsigned short nl = f2bf(yn - bf2f(nh));
    r0->x = (unsigned int)h0 | ((unsigned int)h1 << 16);  // k0,k1: yh.x,yh.y
    r0->y = (unsigned int)h2 | ((unsigned int)l0 << 16);  // k2,k3: yh.z,yl.x
    r0->z = (unsigned int)l1 | ((unsigned int)l2 << 16);  // k4,k5: yl.y,yl.z
    r0->w = (unsigned int)h0 | ((unsigned int)h1 << 16);  // k6,k7: yh.x,yh.y
    r1->x = (unsigned int)h2 | ((unsigned int)nh << 16);  // k8,k9: yh.z,yn_h
    r1->y = (unsigned int)nl;                             // k10, k11=0
    r1->z = 0u; r1->w = 0u;
}

// ---------------------------------------------------------------- min pass
// K-slot scheme (11 of 16 used):
//   A(y): k0-2 yh | k3-5 yl | k6-8 yh | k9 yn_h | k10 yn_l | rest 0
//   B(x): k0-2 -2xh | k3-5 -2xh | k6-8 -2xl | k9 1 | k10 1 | rest 0
//   => T = |y|^2 - 2 x.y (split residual ~1e-4); |x|^2 added post-min in fp32.
// Block = 4 waves; block owns 512 x + 1024 y (single LDS stage, 2 barriers).
// launch_bounds(256,3) -> 168-VGPR budget so MFMA accumulators live in VGPRs
// (R7's (256,4)=128 budget forced AGPR split -> 64 v_accvgpr_read per j-iter).
// LDS 50KB caps residency at 3 blocks/CU anyway, so (256,3) costs nothing.
__global__ __launch_bounds__(256, 3) void minpass_kernel(
        const float* __restrict__ pred,
        const float* __restrict__ full,
        const float* __restrict__ partial,
        float* __restrict__ wsf,
        int ysplit) {
    const int bid = blockIdx.x;          // 8 batches * 36 subs * ysplit
    const int ys  = bid % ysplit;
    const int r   = bid / ysplit;
    const int b   = r / 36;
    const int s   = r % 36;
    const int yhalf = NPTS / ysplit;

    const int t = threadIdx.x;

    // block 0 zeroes acc + counter for the reduce kernel (stream ordering)
    if (bid == 0) {
        if (t < 4) wsf[t] = 0.0f;
        if (t == 4) ((unsigned int*)wsf)[4] = 0u;
    }

    const float* xset; const float* yset; int minoff; int xbase;
    if (s < 16)      { xset = pred;    yset = full; xbase = b*NPTS + s*XBLK;
                       minoff = OFF_SEG + ys*SEG + DIR_PF  + b*NPTS + s*XBLK; }
    else if (s < 32) { xset = full;    yset = pred; xbase = b*NPTS + (s-16)*XBLK;
                       minoff = OFF_SEG + ys*SEG + DIR_FP  + b*NPTS + (s-16)*XBLK; }
    else             { xset = partial; yset = pred; xbase = b*PPTS + (s-32)*XBLK;
                       minoff = OFF_SEG + ys*SEG + DIR_FID + b*PPTS + (s-32)*XBLK; }

    const int lane = t & 63;
    const int wid  = t >> 6;
    const int l31  = lane & 31;
    const int half = lane >> 5;

    __shared__ uint4 sY[2][CHUNK];   // y records [k-half][point]  (32 KB)
    __shared__ uint4 sX[2][XBLK];    // x records                  (16 KB)
    __shared__ float sXn[XBLK];      // |x|^2 fp32                 (2 KB)

    // ---- x prep (16B-stride writes, conflict-free)
    for (int i = t; i < XBLK; i += 256) {
        const float* xp = xset + (size_t)(xbase + i) * 3;
        const float x0 = xp[0], x1 = xp[1], x2 = xp[2];
        const float m0 = -2.0f*x0, m1 = -2.0f*x1, m2 = -2.0f*x2;
        const unsigned short h0 = f2bf(m0), h1 = f2bf(m1), h2 = f2bf(m2);
        const unsigned short l0 = f2bf(m0 - bf2f(h0));
        const unsigned short l1 = f2bf(m1 - bf2f(h1));
        const unsigned short l2 = f2bf(m2 - bf2f(h2));
        const unsigned int one = 0x3F80u;
        uint4 r0, r1;
        r0.x = (unsigned int)h0 | ((unsigned int)h1 << 16);  // k0,k1
        r0.y = (unsigned int)h2 | ((unsigned int)h0 << 16);  // k2,k3
        r0.z = (unsigned int)h1 | ((unsigned int)h2 << 16);  // k4,k5
        r0.w = (unsigned int)l0 | ((unsigned int)l1 << 16);  // k6,k7
        r1.x = (unsigned int)l2 | (one << 16);               // k8,k9
        r1.y = one;                                          // k10,k11=0
        r1.z = 0u; r1.w = 0u;
        sX[0][i] = r0; sX[1][i] = r1;
        sXn[i] = fmaf(x0, x0, fmaf(x1, x1, x2 * x2));
    }

    // ---- y stage: whole 1024-point tile, once (16B-stride writes)
    {
        const float* ypts = yset + (size_t)(b * NPTS + ys * yhalf) * 3;
        for (int i = t; i < CHUNK; i += 256) {
            const float* yp = ypts + (size_t)i * 3;
            uint4 r0, r1;
            encodeY(yp[0], yp[1], yp[2], &r0, &r1);
            sY[0][i] = r0; sY[1][i] = r1;
        }
    }
    __syncthreads();

    const int xw = wid * 128;
    const short8 bf0 = *(const short8*)&sX[half][xw + l31];
    const short8 bf1 = *(const short8*)&sX[half][xw + 32 + l31];
    const short8 bf2 = *(const short8*)&sX[half][xw + 64 + l31];
    const short8 bf3 = *(const short8*)&sX[half][xw + 96 + l31];
    const float  xn0 = sXn[xw + l31];
    const float  xn1 = sXn[xw + 32 + l31];
    const float  xn2 = sXn[xw + 64 + l31];
    const float  xn3 = sXn[xw + 96 + l31];

    const floatx16 zc = {0,0,0,0, 0,0,0,0, 0,0,0,0, 0,0,0,0};
    float cmin0 = 3.4e38f, cmin1 = 3.4e38f, cmin2 = 3.4e38f, cmin3 = 3.4e38f;

    const uint4* sYh = &sY[half][0];
    short8 af = *(const short8*)&sYh[l31];
#pragma unroll 4
    for (int j = 0; j < CHUNK / 32; ++j) {
        // prefetch next A-fragment (wraps on last iter; value unused)
        const short8 afn = *(const short8*)&sYh[((j + 1) & (CHUNK/32 - 1)) * 32 + l31];
        // staggered: overlap MFMA issue with min trees, <=2-3 live accs
        const floatx16 d0 = __builtin_amdgcn_mfma_f32_32x32x16_bf16(af, bf0, zc, 0, 0, 0);
        const floatx16 d1 = __builtin_amdgcn_mfma_f32_32x32x16_bf16(af, bf1, zc, 0, 0, 0);
        cmin0 = min16(d0, cmin0);
        const floatx16 d2 = __builtin_amdgcn_mfma_f32_32x32x16_bf16(af, bf2, zc, 0, 0, 0);
        cmin1 = min16(d1, cmin1);
        const floatx16 d3 = __builtin_amdgcn_mfma_f32_32x32x16_bf16(af, bf3, zc, 0, 0, 0);
        cmin2 = min16(d2, cmin2);
        cmin3 = min16(d3, cmin3);
        af = afn;
    }

    // merge the two lane-halves (same column, different row halves), add |x|^2
    const float m0 = fminf(cmin0, __shfl_xor(cmin0, 32, 64));
    const float m1 = fminf(cmin1, __shfl_xor(cmin1, 32, 64));
    const float m2 = fminf(cmin2, __shfl_xor(cmin2, 32, 64));
    const float m3 = fminf(cmin3, __shfl_xor(cmin3, 32, 64));
    if (lane < 32) {
        wsf[minoff + xw + l31]      = fmaxf(m0 + xn0, 0.0f);
        wsf[minoff + xw + 32 + l31] = fmaxf(m1 + xn1, 0.0f);
        wsf[minoff + xw + 64 + l31] = fmaxf(m2 + xn2, 0.0f);
        wsf[minoff + xw + 96 + l31] = fmaxf(m3 + xn3, 0.0f);
    }
}

// ---------------------------------------------------------------- reductions
__device__ __forceinline__ float waveReduceSum(float v) {
#pragma unroll
    for (int o = 32; o > 0; o >>= 1) v += __shfl_down(v, o, 64);
    return v;
}

__device__ __forceinline__ float blockReduceSum(float v) {
    __shared__ float wsum[4];
    const int lane = threadIdx.x & 63;
    const int wid  = threadIdx.x >> 6;
    v = waveReduceSum(v);
    if (lane == 0) wsum[wid] = v;
    __syncthreads();
    if (wid == 0) {
        v = (lane < ((int)blockDim.x >> 6)) ? wsum[lane] : 0.0f;
        v = waveReduceSum(v);
    }
    return v;
}

// Blocks 0..63: pf (1024 slots each), 64..127: fp, 128..143: fid, 144: kl.
#define NRED_BLOCKS 145
__global__ __launch_bounds__(256) void reduce_finalize_kernel(
        float* __restrict__ wsf,
        const float* __restrict__ mu,
        const float* __restrict__ logvar,
        float* __restrict__ out,
        int ysplit) {
    float* acc = wsf;
    unsigned int* cnt = (unsigned int*)wsf + 4;
    const int bid = blockIdx.x;
    const int t   = threadIdx.x;

    float v = 0.0f;
    int accIdx;
    if (bid < 144) {
        int base;
        if (bid < 64)       { accIdx = 0; base = DIR_PF  + bid * 1024;         }
        else if (bid < 128) { accIdx = 1; base = DIR_FP  + (bid - 64) * 1024;  }
        else                { accIdx = 2; base = DIR_FID + (bid - 128) * 1024; }
#pragma unroll
        for (int k = 0; k < 4; ++k) {
            const int i = OFF_SEG + base + k * 256 + t;
            float m = wsf[i];
            for (int sg = 1; sg < ysplit; ++sg) m = fminf(m, wsf[sg * SEG + i]);
            v += sqrtf(fmaxf(m, 1e-12f));
        }
    } else {
        accIdx = 3;
#pragma unroll
        for (int k = 0; k < BATCH * DLAT / 256; ++k) {
            const int i = k * 256 + t;
            const float m = mu[i];
            const float l = logvar[i];
            v += -0.5f * (1.0f + l - m * m - expf(l));
        }
    }

    v = blockReduceSum(v);
    if (t == 0) {
        atomicAdd(&acc[accIdx], v);
        __threadfence();
        const unsigned int done = atomicAdd(cnt, 1u);
        if (done == NRED_BLOCKS - 1) {
            const float s_pf  = atomicAdd(&acc[0], 0.0f);
            const float s_fp  = atomicAdd(&acc[1], 0.0f);
            const float s_fid = atomicAdd(&acc[2], 0.0f);
            const float s_kl  = atomicAdd(&acc[3], 0.0f);
            const float cd  = 0.5f * (s_pf / (float)(BATCH * NPTS) +
                                      s_fp / (float)(BATCH * NPTS));
            const float fid = s_fid / (float)(BATCH * PPTS);
            const float kl  = s_kl / (float)BATCH;
            out[0] = cd + 0.01f * kl + 0.5f * fid;  // CD_W=1, BETA=0.01, FID_W=0.5
            out[1] = cd;
            out[2] = kl;
            out[3] = fid;
        }
    }
}

// ---------------------------------------------------------------- launch
extern "C" void kernel_launch(void* const* d_in, const int* in_sizes, int n_in,
                              void* d_out, int out_size, void* d_ws, size_t ws_size,
                              hipStream_t stream) {
    const float* pred    = (const float*)d_in[0];
    const float* full    = (const float*)d_in[1];
    const float* partial = (const float*)d_in[2];
    const float* mu      = (const float*)d_in[3];
    const float* logvar  = (const float*)d_in[4];
    float* out = (float*)d_out;
    float* wsf = (float*)d_ws;

    // ysplit chosen from ws capacity (deterministic: ws_size fixed across calls)
    int ysplit = 2;
    if (ws_size >= (size_t)(OFF_SEG + 8 * SEG) * 4) ysplit = 8;
    else if (ws_size >= (size_t)(OFF_SEG + 4 * SEG) * 4) ysplit = 4;

    // 1. MFMA min-distance pass (block 0 also zeroes acc+counter)
    minpass_kernel<<<8 * 36 * ysplit, 256, 0, stream>>>(pred, full, partial, wsf, ysplit);

    // 2. all reductions + finalize in one dispatch
    reduce_finalize_kernel<<<NRED_BLOCKS, 256, 0, stream>>>(wsf, mu, logvar, out, ysplit);
}